// Round 12
// baseline (178.584 us; speedup 1.0000x reference)
//
#include <hip/hip_runtime.h>
#include <stdint.h>
#include <math.h>

typedef __attribute__((ext_vector_type(8))) __bf16 bf16x8;
typedef __attribute__((ext_vector_type(4))) __bf16 bf16x4;
typedef __attribute__((ext_vector_type(4))) float f32x4;

// -------- fragment-major tiled layout for totalbf --------
// 16-row x 32-col fragment blocks in MFMA order. Element (row, o):
//   row-block = row>>4 (4096 elems), col-block = o>>5 (512 elems),
//   inner = q<<7 | n16<<3 | e  with q=(o>>3)&3, n16=row&15, e=o&7.
// Lane l = q*16+n16 owns the 8 elems at +l*8: one 16x32 fragment = ONE
// coalesced 1KB wave-load (dwordx4/lane). Verified R11.
__device__ __forceinline__ size_t tbidx(int row, int o) {
  return ((size_t)(row >> 4) << 12) + ((o >> 5) << 9) +
         (((o >> 3) & 3) << 7) + ((row & 15) << 3) + (o & 7);
}

// ---------------- outs GEMM: C[m][n] = sum_k x[m][k] * Wflat[n][k] + bias[n] ----
// R12: retiled 64x64 -> 64x32 (M x N) => grid (16,64) = 1024 blocks = 4/CU,
// 4 waves/SIMD (was 2) — occupancy was the binding constraint (outs ~45us at
// 2 waves/SIMD with only 8 MFMAs of latency cover per iter). Same proven
// staging (reg-staged bf16, XOR swizzle, prefetch-after-barrier).
// Wave (wr,wc): rows wr*32..+32, cols wc*16..+16 -> acc[2][1].
// Block (0,0) zero-inits the atomic accumulators + final scalar.
__global__ __launch_bounds__(256) void k_outs(const float* __restrict__ x,
                                              const float* __restrict__ W,
                                              const float* __restrict__ bias,
                                              __bf16* __restrict__ totalbf,
                                              float* __restrict__ colsum,
                                              float* __restrict__ scal,
                                              float* __restrict__ out) {
  __shared__ __bf16 As[64][64];   // M-rows x K
  __shared__ __bf16 Bs[32][64];   // N-rows x K
  const int bj = blockIdx.x;   // 0..15 (N tiles of 32)
  const int bi = blockIdx.y;   // 0..63 (M tiles of 64)
  const int t = threadIdx.x;
  if (bj == 0 && bi == 0) {
    colsum[t] = 0.f;
    if (t < 8) scal[t] = 0.f;
    if (t == 0) out[1048576] = 0.f;
  }
  const int wid = t >> 6, lane = t & 63;
  const int wr = wid >> 1, wc = wid & 1;
  const int n16 = lane & 15, q = lane >> 4;
  const int sx = (n16 & 7) << 3;        // read-side swizzle (element units)
  const int erow = t >> 4;              // 0..15 (+p*16)
  const int c4 = (t & 15) << 2;         // 0..60

  f32x4 acc[2];
  f32x4 zero = {0.f, 0.f, 0.f, 0.f};
  acc[0] = zero; acc[1] = zero;

  const int arow0 = bi * 64, brow0 = bj * 32;

  float4 ra[4], rb[2];
#pragma unroll
  for (int p = 0; p < 4; ++p)
    ra[p] = *(const float4*)(x + (size_t)(arow0 + p * 16 + erow) * 512 + c4);
#pragma unroll
  for (int p = 0; p < 2; ++p)
    rb[p] = *(const float4*)(W + (size_t)(brow0 + p * 16 + erow) * 512 + c4);

  for (int kc = 0; kc < 512; kc += 64) {
#pragma unroll
    for (int p = 0; p < 4; ++p) {
      int row = p * 16 + erow;
      int col = c4 ^ ((row & 7) << 3);
      float4 va = ra[p];
      bf16x4 ba = {(__bf16)va.x, (__bf16)va.y, (__bf16)va.z, (__bf16)va.w};
      *(bf16x4*)&As[row][col] = ba;
    }
#pragma unroll
    for (int p = 0; p < 2; ++p) {
      int row = p * 16 + erow;
      int col = c4 ^ ((row & 7) << 3);
      float4 vb = rb[p];
      bf16x4 bb = {(__bf16)vb.x, (__bf16)vb.y, (__bf16)vb.z, (__bf16)vb.w};
      *(bf16x4*)&Bs[row][col] = bb;
    }
    __syncthreads();
    // issue next-tile global loads AFTER the barrier: they fly under the MFMAs
    if (kc < 448) {
#pragma unroll
      for (int p = 0; p < 4; ++p)
        ra[p] = *(const float4*)(x + (size_t)(arow0 + p * 16 + erow) * 512 + kc + 64 + c4);
#pragma unroll
      for (int p = 0; p < 2; ++p)
        rb[p] = *(const float4*)(W + (size_t)(brow0 + p * 16 + erow) * 512 + kc + 64 + c4);
    }
#pragma unroll
    for (int ks = 0; ks < 2; ++ks) {
      bf16x8 af[2], bfr;
#pragma unroll
      for (int f = 0; f < 2; ++f)
        af[f] = *(const bf16x8*)&As[wr * 32 + f * 16 + n16][(ks * 32 + q * 8) ^ sx];
      bfr = *(const bf16x8*)&Bs[wc * 16 + n16][(ks * 32 + q * 8) ^ sx];
      for (int fr = 0; fr < 2; ++fr)
        acc[fr] = __builtin_amdgcn_mfma_f32_16x16x32_bf16(af[fr], bfr, acc[fr], 0, 0, 0);
    }
    __syncthreads();
  }

  {
    int n_g = bj * 32 + wc * 16 + n16;   // 0..511
    float bv = bias[n_g];
    int l = n_g >> 8, o = n_g & 255;
    for (int fr = 0; fr < 2; ++fr) {
      for (int r = 0; r < 4; ++r) {
        int m_g = bi * 64 + wr * 32 + fr * 16 + q * 4 + r;
        float v = acc[fr][r] + bv;
        totalbf[tbidx(l * 4096 + m_g, o)] = (__bf16)v;
      }
    }
  }
}

// ------- fused: gates + sq + colsum + combine + bandwidth finalize ------------
// R12: 512 blocks (was 128 — only 0.5 waves/SIMD on half the chip, every load
// latency fully exposed). Now 2048 waves = 2/SIMD chip-wide. 8 rows/block,
// 2 per wave. Math identical; finalizer counter -> 511.
__global__ __launch_bounds__(256) void k_sqc(const __bf16* __restrict__ tot,
                                             const float* __restrict__ x,
                                             const float* __restrict__ Waux,
                                             const float* __restrict__ baux,
                                             float* __restrict__ sq,
                                             float* __restrict__ colsum,
                                             float* __restrict__ scal,
                                             float* __restrict__ out) {
  __shared__ float lcol[4][256];
  __shared__ float wsq[4];
  __shared__ unsigned int isLast;
  const int t = threadIdx.x;
  const int wave = t >> 6, lane = t & 63;

  // ---- gates phase: rows m = blk*8 + wave*2 + it ----
  const float4* wa = (const float4*)(Waux);          // row 0: 128 float4
  const float4* wb = (const float4*)(Waux + 512);    // row 1
  float4 a0 = wa[lane * 2], a1 = wa[lane * 2 + 1];
  float4 b0 = wb[lane * 2], b1 = wb[lane * 2 + 1];
  const float bx0 = baux[0], bx1 = baux[1];
  float g0[2], g1[2];
#pragma unroll
  for (int it = 0; it < 2; ++it) {
    int m = blockIdx.x * 8 + wave * 2 + it;
    const float4* xr = (const float4*)(x + (size_t)m * 512);
    float4 x0 = xr[lane * 2], x1 = xr[lane * 2 + 1];
    float p0 = x0.x * a0.x + x0.y * a0.y + x0.z * a0.z + x0.w * a0.w
             + x1.x * a1.x + x1.y * a1.y + x1.z * a1.z + x1.w * a1.w;
    float p1 = x0.x * b0.x + x0.y * b0.y + x0.z * b0.z + x0.w * b0.w
             + x1.x * b1.x + x1.y * b1.y + x1.z * b1.z + x1.w * b1.w;
    for (int off = 32; off; off >>= 1) {
      p0 += __shfl_xor(p0, off, 64);
      p1 += __shfl_xor(p1, off, 64);
    }
    p0 += bx0; p1 += bx1;
    float mm = fmaxf(p0, p1);
    float e0 = __expf(p0 - mm), e1 = __expf(p1 - mm);
    float inv = 1.f / (e0 + e1);
    g0[it] = e0 * inv;
    g1[it] = e1 * inv;
  }

  // ---- sq + colsum + combine ----
  float c0 = 0.f, c1 = 0.f, c2 = 0.f, c3 = 0.f;
  float bsq = 0.f;
#pragma unroll
  for (int it = 0; it < 2; ++it) {
    int m = blockIdx.x * 8 + wave * 2 + it;       // 0..4095
    bf16x4 v0 = *(const bf16x4*)(tot + tbidx(m, lane * 4));
    bf16x4 v1 = *(const bf16x4*)(tot + tbidx(4096 + m, lane * 4));
    float f00 = v0[0], f01 = v0[1], f02 = v0[2], f03 = v0[3];
    float f10 = v1[0], f11 = v1[1], f12 = v1[2], f13 = v1[3];
    float s0 = f00 * f00 + f01 * f01 + f02 * f02 + f03 * f03;
    float s1 = f10 * f10 + f11 * f11 + f12 * f12 + f13 * f13;
    for (int off = 32; off; off >>= 1) {
      s0 += __shfl_down(s0, off, 64);
      s1 += __shfl_down(s1, off, 64);
    }
    if (lane == 0) { sq[m] = s0; sq[4096 + m] = s1; bsq += s0 + s1; }
    c0 += f00 + f10; c1 += f01 + f11; c2 += f02 + f12; c3 += f03 + f13;
    float4 r;
    r.x = g0[it] * f00 + g1[it] * f10;
    r.y = g0[it] * f01 + g1[it] * f11;
    r.z = g0[it] * f02 + g1[it] * f12;
    r.w = g0[it] * f03 + g1[it] * f13;
    *(float4*)(out + (size_t)m * 256 + lane * 4) = r;
  }
  lcol[wave][lane * 4 + 0] = c0;
  lcol[wave][lane * 4 + 1] = c1;
  lcol[wave][lane * 4 + 2] = c2;
  lcol[wave][lane * 4 + 3] = c3;
  if (lane == 0) wsq[wave] = bsq;
  __syncthreads();
  float s2 = lcol[0][t] + lcol[1][t] + lcol[2][t] + lcol[3][t];
  atomicAdd(&colsum[t], s2);
  if (t == 0) atomicAdd(&scal[4], wsq[0] + wsq[1] + wsq[2] + wsq[3]);
  __threadfence();
  if (t == 0) {
    unsigned int c = atomicAdd((unsigned int*)(scal + 5), 1u);
    isLast = (c == 511u) ? 1u : 0u;
  }
  __syncthreads();
  if (isLast) {
    __threadfence();
    float cv = atomicAdd(&colsum[t], 0.0f);      // coherent read
    lcol[0][t] = cv * cv;
    __syncthreads();
    for (int off = 128; off; off >>= 1) {
      if (t < off) lcol[0][t] += lcol[0][t + off];
      __syncthreads();
    }
    if (t == 0) {
      float sumsq = atomicAdd(&scal[4], 0.0f);
      double sumdist = 2.0 * 8192.0 * (double)sumsq - 2.0 * (double)lcol[0][0];
      double bw = sumdist / (8192.0 * 8192.0 - 8192.0) / 4.0;  // / KERNEL_MUL^(5//2)
      scal[1] = (float)(1.4426950408889634 / (bw * 16.0));     // g4 * log2(e)
      scal[2] = (float)bw;
    }
  }
}

// ---------------- Gram tiles + fused multi-bandwidth kernel sum ---------------
// R11-proven direct-fragment (45.1 us): fragment-major totalbf, each 16x32
// A/B fragment is ONE coalesced 1KB wave-load; no LDS tiles, no barriers.
// Triangular XCD-chunked grid, fire-and-forget atomic with final scale folded
// in. UNCHANGED.
__global__ __launch_bounds__(256) void k_gram(const __bf16* __restrict__ tot,
                                              const float* __restrict__ sq,
                                              const float* __restrict__ scal,
                                              float* __restrict__ out) {
  const int b = blockIdx.x;                    // 0..2079
  const int nid = (b & 7) * 260 + (b >> 3);    // XCD-chunked, bijective (2080=8*260)
  int ti = (int)((129.0 - sqrt(129.0 * 129.0 - 8.0 * (double)nid)) * 0.5);
  while (64 * ti - ti * (ti - 1) / 2 > nid) --ti;
  while (64 * (ti + 1) - (ti + 1) * ti / 2 <= nid) ++ti;
  const int tj = ti + (nid - (64 * ti - ti * (ti - 1) / 2));

  __shared__ float sqi[128], sqj[128];
  __shared__ float wred[4];
  const int t = threadIdx.x;
  const int wid = t >> 6, lane = t & 63;
  const int wr = wid >> 1, wc = wid & 1;
  const int n16 = lane & 15, q = lane >> 4;

  const float g = scal[1];           // log2e / (bw*16)
  if (t < 128) sqi[t] = sq[ti * 128 + t] * g;          // pre-scaled by g
  else         sqj[t - 128] = sq[tj * 128 + (t - 128)] * g;

  f32x4 acc[4][4];
  f32x4 zero = {0.f, 0.f, 0.f, 0.f};
  for (int i = 0; i < 4; ++i)
    for (int j = 0; j < 4; ++j) acc[i][j] = zero;

  // fragment bases: A-frag f covers rows ti*128+wr*64+f*16..+16 — row-block
  // (ti*8+wr*4+f); lane l's 16B slice at +l*8 elems; col-block ks at +ks*512.
  const __bf16* pA = tot + ((size_t)(ti * 8 + wr * 4) << 12) + lane * 8;
  const __bf16* pB = tot + ((size_t)(tj * 8 + wc * 4) << 12) + lane * 8;

#pragma unroll
  for (int ks = 0; ks < 8; ++ks) {
    bf16x8 af[4], bfr[4];
#pragma unroll
    for (int f = 0; f < 4; ++f) {
      af[f]  = *(const bf16x8*)(pA + ((size_t)f << 12) + ((size_t)ks << 9));
      bfr[f] = *(const bf16x8*)(pB + ((size_t)f << 12) + ((size_t)ks << 9));
    }
    for (int fr = 0; fr < 4; ++fr)
      for (int fc = 0; fc < 4; ++fc)
        acc[fr][fc] = __builtin_amdgcn_mfma_f32_16x16x32_bf16(af[fr], bfr[fc], acc[fr][fc], 0, 0, 0);
  }

  __syncthreads();   // publish sqi/sqj (cross-wave)

  // epilogue: arg = 2g*acc - (g*si + g*sj); ksum = u+u2+u4+u8+u16, u=exp2(arg)
  const float twog = 2.f * g;
  float lsum = 0.f;
  for (int fr = 0; fr < 4; ++fr) {
    for (int r = 0; r < 4; ++r) {
      float gsi = sqi[wr * 64 + fr * 16 + q * 4 + r];
      for (int fc = 0; fc < 4; ++fc) {
        float gsj = sqj[wc * 64 + fc * 16 + n16];
        float u = exp2f(fmaf(twog, acc[fr][fc][r], -(gsi + gsj)));
        float u2 = u * u, u4 = u2 * u2, u8 = u4 * u4;
        float s1 = fmaf(u8, u8, u8);           // u16 + u8
        lsum += (u + u2) + (u4 + s1);
      }
    }
  }
  for (int off = 32; off; off >>= 1) lsum += __shfl_down(lsum, off, 64);
  if (lane == 0) wred[wid] = lsum;
  __syncthreads();
  if (t == 0) {
    float blocksum = wred[0] + wred[1] + wred[2] + wred[3];
    float sgn = ((ti < 32) == (tj < 32)) ? 1.f : -1.f;
    float wgt = (ti == tj) ? sgn : 2.f * sgn;
    // final scale folded in: out[1048576] = -S/2^24, accumulated directly
    atomicAdd(out + 1048576, wgt * blocksum * (-1.f / 16777216.f));
  }
}

extern "C" void kernel_launch(void* const* d_in, const int* in_sizes, int n_in,
                              void* d_out, int out_size, void* d_ws, size_t ws_size,
                              hipStream_t stream) {
  const float* x    = (const float*)d_in[0];
  const float* Waux = (const float*)d_in[1];
  const float* baux = (const float*)d_in[2];
  const float* W    = (const float*)d_in[3];
  const float* bias = (const float*)d_in[4];
  float* out = (float*)d_out;

  char* ws = (char*)d_ws;
  __bf16* totalbf = (__bf16*)ws;                    // 8192*256*2 = 4,194,304 B (tiled)
  float* sq      = (float*)(ws + 4194304);          // 8192 f32
  float* colsum  = (float*)(ws + 4227072);          // 256 f32
  float* scal    = (float*)(ws + 4228096);          // [1]=g4l2 [2]=bw [4]=sumsq [5]=sqc-cnt

  k_outs<<<dim3(16, 64), 256, 0, stream>>>(x, W, bias, totalbf, colsum, scal, out);
  k_sqc<<<512, 256, 0, stream>>>(totalbf, x, Waux, baux, sq, colsum, scal, out);
  k_gram<<<2080, 256, 0, stream>>>(totalbf, sq, scal, out);
}

// Round 13
// 154.614 us; speedup vs baseline: 1.1550x; 1.1550x over previous
//
#include <hip/hip_runtime.h>
#include <stdint.h>
#include <math.h>

typedef __attribute__((ext_vector_type(8))) __bf16 bf16x8;
typedef __attribute__((ext_vector_type(4))) __bf16 bf16x4;
typedef __attribute__((ext_vector_type(4))) float f32x4;

// -------- fragment-major tiled layout for totalbf --------
// 16-row x 32-col fragment blocks in MFMA order. Element (row, o):
//   row-block = row>>4 (4096 elems), col-block = o>>5 (512 elems),
//   inner = q<<7 | n16<<3 | e  with q=(o>>3)&3, n16=row&15, e=o&7.
// Lane l = q*16+n16 owns the 8 elems at +l*8: one 16x32 fragment = ONE
// coalesced 1KB wave-load (dwordx4/lane). Verified R11.
__device__ __forceinline__ size_t tbidx(int row, int o) {
  return ((size_t)(row >> 4) << 12) + ((o >> 5) << 9) +
         (((o >> 3) & 3) << 7) + ((row & 15) << 3) + (o & 7);
}

// ---------------- outs GEMM: C[m][n] = sum_k x[m][k] * Wflat[n][k] + bias[n] ----
// R11-EXACT (64x64 tiles, grid (8,64)) — R12's 64x32 retile regressed (halved
// MFMA cover per iter, raised panel redundancy). Reg-staged bf16, XOR swizzle,
// prefetch-after-barrier. Epilogue stores fragment-major.
// Block (0,0) zero-inits scal + final scalar (colsum now atomic-free).
__global__ __launch_bounds__(256) void k_outs(const float* __restrict__ x,
                                              const float* __restrict__ W,
                                              const float* __restrict__ bias,
                                              __bf16* __restrict__ totalbf,
                                              float* __restrict__ scal,
                                              float* __restrict__ out) {
  __shared__ __bf16 As[64][64];
  __shared__ __bf16 Bs[64][64];
  const int bj = blockIdx.x;   // 0..7  (N tiles of 64)
  const int bi = blockIdx.y;   // 0..63 (M tiles of 64)
  const int t = threadIdx.x;
  if (bj == 0 && bi == 0) {
    if (t < 8) scal[t] = 0.f;
    if (t == 0) out[1048576] = 0.f;
  }
  const int wid = t >> 6, lane = t & 63;
  const int wr = wid >> 1, wc = wid & 1;
  const int n16 = lane & 15, q = lane >> 4;
  const int sx = (n16 & 7) << 3;        // read-side swizzle (element units)
  const int erow = t >> 4;              // 0..15 (+p*16)
  const int c4 = (t & 15) << 2;         // 0..60

  f32x4 acc[2][2];
  f32x4 zero = {0.f, 0.f, 0.f, 0.f};
  for (int i = 0; i < 2; ++i)
    for (int j = 0; j < 2; ++j) acc[i][j] = zero;

  const int arow0 = bi * 64, brow0 = bj * 64;

  float4 ra[4], rb[4];
#pragma unroll
  for (int p = 0; p < 4; ++p) {
    int row = p * 16 + erow;
    ra[p] = *(const float4*)(x + (size_t)(arow0 + row) * 512 + c4);
    rb[p] = *(const float4*)(W + (size_t)(brow0 + row) * 512 + c4);
  }

  for (int kc = 0; kc < 512; kc += 64) {
#pragma unroll
    for (int p = 0; p < 4; ++p) {
      int row = p * 16 + erow;
      int col = c4 ^ ((row & 7) << 3);
      float4 va = ra[p];
      bf16x4 ba = {(__bf16)va.x, (__bf16)va.y, (__bf16)va.z, (__bf16)va.w};
      *(bf16x4*)&As[row][col] = ba;
      float4 vb = rb[p];
      bf16x4 bb = {(__bf16)vb.x, (__bf16)vb.y, (__bf16)vb.z, (__bf16)vb.w};
      *(bf16x4*)&Bs[row][col] = bb;
    }
    __syncthreads();
    // issue next-tile global loads AFTER the barrier: they fly under the MFMAs
    if (kc < 448) {
#pragma unroll
      for (int p = 0; p < 4; ++p) {
        int row = p * 16 + erow;
        ra[p] = *(const float4*)(x + (size_t)(arow0 + row) * 512 + kc + 64 + c4);
        rb[p] = *(const float4*)(W + (size_t)(brow0 + row) * 512 + kc + 64 + c4);
      }
    }
#pragma unroll
    for (int ks = 0; ks < 2; ++ks) {
      bf16x8 af[2], bfr[2];
#pragma unroll
      for (int f = 0; f < 2; ++f) {
        af[f]  = *(const bf16x8*)&As[wr * 32 + f * 16 + n16][(ks * 32 + q * 8) ^ sx];
        bfr[f] = *(const bf16x8*)&Bs[wc * 32 + f * 16 + n16][(ks * 32 + q * 8) ^ sx];
      }
      for (int fr = 0; fr < 2; ++fr)
        for (int fc = 0; fc < 2; ++fc)
          acc[fr][fc] = __builtin_amdgcn_mfma_f32_16x16x32_bf16(af[fr], bfr[fc], acc[fr][fc], 0, 0, 0);
    }
    __syncthreads();
  }

  for (int fc = 0; fc < 2; ++fc) {
    int n_g = bj * 64 + wc * 32 + fc * 16 + n16;   // 0..511
    float bv = bias[n_g];
    int l = n_g >> 8, o = n_g & 255;
    for (int fr = 0; fr < 2; ++fr) {
      for (int r = 0; r < 4; ++r) {
        int m_g = bi * 64 + wr * 32 + fr * 16 + q * 4 + r;
        float v = acc[fr][fc][r] + bv;
        totalbf[tbidx(l * 4096 + m_g, o)] = (__bf16)v;
      }
    }
  }
}

// ------- fused: gates + sq + colsum + combine + bandwidth finalize ------------
// R13: (a) SIGMOID gates — softmax over 2 logits needs only d = x.(w0-w1):
//      half the dot FLOPs, half the shuffle chain. (b) colsum via per-block
//      partials (plain coalesced stores) — R12 showed per-thread atomicAdd to
//      colsum[256] serializes (131K same-line RMWs); finalizer sums partials.
//      (c) 256 blocks = 1 wave/SIMD chip-wide (safe now that atomics are gone).
__global__ __launch_bounds__(256) void k_sqc(const __bf16* __restrict__ tot,
                                             const float* __restrict__ x,
                                             const float* __restrict__ Waux,
                                             const float* __restrict__ baux,
                                             float* __restrict__ sq,
                                             float* __restrict__ cpart,
                                             float* __restrict__ scal,
                                             float* __restrict__ out) {
  __shared__ float lcol[4][256];
  __shared__ float wsq[4];
  __shared__ unsigned int isLast;
  const int t = threadIdx.x;
  const int wave = t >> 6, lane = t & 63;

  // ---- gates: d = x.(w0-w1) + (b0-b1); g0 = sigmoid(d), g1 = 1-g0 ----
  const float4* wa = (const float4*)(Waux);          // row 0: 128 float4
  const float4* wb = (const float4*)(Waux + 512);    // row 1
  float4 wa0 = wa[lane * 2], wa1 = wa[lane * 2 + 1];
  float4 wb0 = wb[lane * 2], wb1 = wb[lane * 2 + 1];
  float4 wd0 = {wa0.x - wb0.x, wa0.y - wb0.y, wa0.z - wb0.z, wa0.w - wb0.w};
  float4 wd1 = {wa1.x - wb1.x, wa1.y - wb1.y, wa1.z - wb1.z, wa1.w - wb1.w};
  const float bd = baux[0] - baux[1];
  float g0[4], g1[4];
#pragma unroll
  for (int it = 0; it < 4; ++it) {
    int m = blockIdx.x * 16 + wave * 4 + it;
    const float4* xr = (const float4*)(x + (size_t)m * 512);
    float4 x0 = xr[lane * 2], x1 = xr[lane * 2 + 1];
    float d = x0.x * wd0.x + x0.y * wd0.y + x0.z * wd0.z + x0.w * wd0.w
            + x1.x * wd1.x + x1.y * wd1.y + x1.z * wd1.z + x1.w * wd1.w;
    for (int off = 32; off; off >>= 1) d += __shfl_xor(d, off, 64);
    d += bd;
    float g = 1.f / (1.f + __expf(-d));
    g0[it] = g;
    g1[it] = 1.f - g;
  }

  // ---- sq + colsum + combine ----
  float c0 = 0.f, c1 = 0.f, c2 = 0.f, c3 = 0.f;
  float bsq = 0.f;
#pragma unroll
  for (int it = 0; it < 4; ++it) {
    int m = blockIdx.x * 16 + wave * 4 + it;      // 0..4095
    bf16x4 v0 = *(const bf16x4*)(tot + tbidx(m, lane * 4));
    bf16x4 v1 = *(const bf16x4*)(tot + tbidx(4096 + m, lane * 4));
    float f00 = v0[0], f01 = v0[1], f02 = v0[2], f03 = v0[3];
    float f10 = v1[0], f11 = v1[1], f12 = v1[2], f13 = v1[3];
    float s0 = f00 * f00 + f01 * f01 + f02 * f02 + f03 * f03;
    float s1 = f10 * f10 + f11 * f11 + f12 * f12 + f13 * f13;
    for (int off = 32; off; off >>= 1) {
      s0 += __shfl_down(s0, off, 64);
      s1 += __shfl_down(s1, off, 64);
    }
    if (lane == 0) { sq[m] = s0; sq[4096 + m] = s1; bsq += s0 + s1; }
    c0 += f00 + f10; c1 += f01 + f11; c2 += f02 + f12; c3 += f03 + f13;
    float4 r;
    r.x = g0[it] * f00 + g1[it] * f10;
    r.y = g0[it] * f01 + g1[it] * f11;
    r.z = g0[it] * f02 + g1[it] * f12;
    r.w = g0[it] * f03 + g1[it] * f13;
    *(float4*)(out + (size_t)m * 256 + lane * 4) = r;
  }
  lcol[wave][lane * 4 + 0] = c0;
  lcol[wave][lane * 4 + 1] = c1;
  lcol[wave][lane * 4 + 2] = c2;
  lcol[wave][lane * 4 + 3] = c3;
  if (lane == 0) wsq[wave] = bsq;
  __syncthreads();
  // per-block colsum partial: plain coalesced store, NO atomics
  cpart[(size_t)blockIdx.x * 256 + t] =
      lcol[0][t] + lcol[1][t] + lcol[2][t] + lcol[3][t];
  if (t == 0) atomicAdd(&scal[4], wsq[0] + wsq[1] + wsq[2] + wsq[3]);
  __threadfence();
  if (t == 0) {
    unsigned int c = atomicAdd((unsigned int*)(scal + 5), 1u);
    isLast = (c == 255u) ? 1u : 0u;
  }
  __syncthreads();
  if (isLast) {
    __threadfence();
    float cs = 0.f;
    for (int b2 = 0; b2 < 256; ++b2) cs += cpart[(size_t)b2 * 256 + t];
    lcol[0][t] = cs * cs;
    __syncthreads();
    for (int off = 128; off; off >>= 1) {
      if (t < off) lcol[0][t] += lcol[0][t + off];
      __syncthreads();
    }
    if (t == 0) {
      float sumsq = atomicAdd(&scal[4], 0.0f);
      double sumdist = 2.0 * 8192.0 * (double)sumsq - 2.0 * (double)lcol[0][0];
      double bw = sumdist / (8192.0 * 8192.0 - 8192.0) / 4.0;  // / KERNEL_MUL^(5//2)
      scal[1] = (float)(1.4426950408889634 / (bw * 16.0));     // g4 * log2(e)
      scal[2] = (float)bw;
    }
  }
}

// ---------------- Gram tiles + fused multi-bandwidth kernel sum ---------------
// R11-proven direct-fragment (45.1 us): fragment-major totalbf, each 16x32
// A/B fragment is ONE coalesced 1KB wave-load; no LDS tiles, no barriers.
// Triangular XCD-chunked grid, fire-and-forget atomic with final scale folded
// in. UNCHANGED.
__global__ __launch_bounds__(256) void k_gram(const __bf16* __restrict__ tot,
                                              const float* __restrict__ sq,
                                              const float* __restrict__ scal,
                                              float* __restrict__ out) {
  const int b = blockIdx.x;                    // 0..2079
  const int nid = (b & 7) * 260 + (b >> 3);    // XCD-chunked, bijective (2080=8*260)
  int ti = (int)((129.0 - sqrt(129.0 * 129.0 - 8.0 * (double)nid)) * 0.5);
  while (64 * ti - ti * (ti - 1) / 2 > nid) --ti;
  while (64 * (ti + 1) - (ti + 1) * ti / 2 <= nid) ++ti;
  const int tj = ti + (nid - (64 * ti - ti * (ti - 1) / 2));

  __shared__ float sqi[128], sqj[128];
  __shared__ float wred[4];
  const int t = threadIdx.x;
  const int wid = t >> 6, lane = t & 63;
  const int wr = wid >> 1, wc = wid & 1;
  const int n16 = lane & 15, q = lane >> 4;

  const float g = scal[1];           // log2e / (bw*16)
  if (t < 128) sqi[t] = sq[ti * 128 + t] * g;          // pre-scaled by g
  else         sqj[t - 128] = sq[tj * 128 + (t - 128)] * g;

  f32x4 acc[4][4];
  f32x4 zero = {0.f, 0.f, 0.f, 0.f};
  for (int i = 0; i < 4; ++i)
    for (int j = 0; j < 4; ++j) acc[i][j] = zero;

  // fragment bases: A-frag f covers rows ti*128+wr*64+f*16..+16 — row-block
  // (ti*8+wr*4+f); lane l's 16B slice at +l*8 elems; col-block ks at +ks*512.
  const __bf16* pA = tot + ((size_t)(ti * 8 + wr * 4) << 12) + lane * 8;
  const __bf16* pB = tot + ((size_t)(tj * 8 + wc * 4) << 12) + lane * 8;

#pragma unroll
  for (int ks = 0; ks < 8; ++ks) {
    bf16x8 af[4], bfr[4];
#pragma unroll
    for (int f = 0; f < 4; ++f) {
      af[f]  = *(const bf16x8*)(pA + ((size_t)f << 12) + ((size_t)ks << 9));
      bfr[f] = *(const bf16x8*)(pB + ((size_t)f << 12) + ((size_t)ks << 9));
    }
    for (int fr = 0; fr < 4; ++fr)
      for (int fc = 0; fc < 4; ++fc)
        acc[fr][fc] = __builtin_amdgcn_mfma_f32_16x16x32_bf16(af[fr], bfr[fc], acc[fr][fc], 0, 0, 0);
  }

  __syncthreads();   // publish sqi/sqj (cross-wave)

  // epilogue: arg = 2g*acc - (g*si + g*sj); ksum = u+u2+u4+u8+u16, u=exp2(arg)
  const float twog = 2.f * g;
  float lsum = 0.f;
  for (int fr = 0; fr < 4; ++fr) {
    for (int r = 0; r < 4; ++r) {
      float gsi = sqi[wr * 64 + fr * 16 + q * 4 + r];
      for (int fc = 0; fc < 4; ++fc) {
        float gsj = sqj[wc * 64 + fc * 16 + n16];
        float u = exp2f(fmaf(twog, acc[fr][fc][r], -(gsi + gsj)));
        float u2 = u * u, u4 = u2 * u2, u8 = u4 * u4;
        float s1 = fmaf(u8, u8, u8);           // u16 + u8
        lsum += (u + u2) + (u4 + s1);
      }
    }
  }
  for (int off = 32; off; off >>= 1) lsum += __shfl_down(lsum, off, 64);
  if (lane == 0) wred[wid] = lsum;
  __syncthreads();
  if (t == 0) {
    float blocksum = wred[0] + wred[1] + wred[2] + wred[3];
    float sgn = ((ti < 32) == (tj < 32)) ? 1.f : -1.f;
    float wgt = (ti == tj) ? sgn : 2.f * sgn;
    // final scale folded in: out[1048576] = -S/2^24, accumulated directly
    atomicAdd(out + 1048576, wgt * blocksum * (-1.f / 16777216.f));
  }
}

extern "C" void kernel_launch(void* const* d_in, const int* in_sizes, int n_in,
                              void* d_out, int out_size, void* d_ws, size_t ws_size,
                              hipStream_t stream) {
  const float* x    = (const float*)d_in[0];
  const float* Waux = (const float*)d_in[1];
  const float* baux = (const float*)d_in[2];
  const float* W    = (const float*)d_in[3];
  const float* bias = (const float*)d_in[4];
  float* out = (float*)d_out;

  char* ws = (char*)d_ws;
  __bf16* totalbf = (__bf16*)ws;                    // 8192*256*2 = 4,194,304 B (tiled)
  float* sq      = (float*)(ws + 4194304);          // 8192 f32 -> ends 4227072
  float* cpart   = (float*)(ws + 4227072);          // 256*256 f32 partials -> ends 4489216
  float* scal    = (float*)(ws + 4489216);          // [1]=g4l2 [2]=bw [4]=sumsq [5]=cnt

  k_outs<<<dim3(8, 64), 256, 0, stream>>>(x, W, bias, totalbf, scal, out);
  k_sqc<<<256, 256, 0, stream>>>(totalbf, x, Waux, baux, sq, cpart, scal, out);
  k_gram<<<2080, 256, 0, stream>>>(totalbf, sq, scal, out);
}

// Round 14
// 140.105 us; speedup vs baseline: 1.2746x; 1.1036x over previous
//
#include <hip/hip_runtime.h>
#include <stdint.h>
#include <math.h>

typedef __attribute__((ext_vector_type(8))) __bf16 bf16x8;
typedef __attribute__((ext_vector_type(4))) __bf16 bf16x4;
typedef __attribute__((ext_vector_type(4))) float f32x4;

// -------- fragment-major tiled layout for totalbf --------
// 16-row x 32-col fragment blocks in MFMA order. Element (row, o):
//   row-block = row>>4 (4096 elems), col-block = o>>5 (512 elems),
//   inner = q<<7 | n16<<3 | e  with q=(o>>3)&3, n16=row&15, e=o&7.
// Lane l = q*16+n16 owns the 8 elems at +l*8: one 16x32 fragment = ONE
// coalesced 1KB wave-load (dwordx4/lane). Verified R11.
__device__ __forceinline__ size_t tbidx(int row, int o) {
  return ((size_t)(row >> 4) << 12) + ((o >> 5) << 9) +
         (((o >> 3) & 3) << 7) + ((row & 15) << 3) + (o & 7);
}

// ---------------- outs GEMM: C[m][n] = sum_k x[m][k] * Wflat[n][k] + bias[n] ----
// R12-MEASURED variant (~26 us by subtraction): 64x32 tiles, grid (16,64) =
// 1024 blocks = 4 blocks/CU = 4 waves/SIMD. R12's regression was k_sqc, not
// this retile — occupancy 2->4 waves/SIMD beats the halved per-iter MFMA.
// Reg-staged bf16, XOR swizzle, prefetch-after-barrier; fragment-major store.
// Block (0,0) zero-inits colsum + scal + final scalar.
__global__ __launch_bounds__(256) void k_outs(const float* __restrict__ x,
                                              const float* __restrict__ W,
                                              const float* __restrict__ bias,
                                              __bf16* __restrict__ totalbf,
                                              float* __restrict__ colsum,
                                              float* __restrict__ scal,
                                              float* __restrict__ out) {
  __shared__ __bf16 As[64][64];   // M-rows x K
  __shared__ __bf16 Bs[32][64];   // N-rows x K
  const int bj = blockIdx.x;   // 0..15 (N tiles of 32)
  const int bi = blockIdx.y;   // 0..63 (M tiles of 64)
  const int t = threadIdx.x;
  if (bj == 0 && bi == 0) {
    colsum[t] = 0.f;
    if (t < 8) scal[t] = 0.f;
    if (t == 0) out[1048576] = 0.f;
  }
  const int wid = t >> 6, lane = t & 63;
  const int wr = wid >> 1, wc = wid & 1;
  const int n16 = lane & 15, q = lane >> 4;
  const int sx = (n16 & 7) << 3;        // read-side swizzle (element units)
  const int erow = t >> 4;              // 0..15 (+p*16)
  const int c4 = (t & 15) << 2;         // 0..60

  f32x4 acc[2];
  f32x4 zero = {0.f, 0.f, 0.f, 0.f};
  acc[0] = zero; acc[1] = zero;

  const int arow0 = bi * 64, brow0 = bj * 32;

  float4 ra[4], rb[2];
#pragma unroll
  for (int p = 0; p < 4; ++p)
    ra[p] = *(const float4*)(x + (size_t)(arow0 + p * 16 + erow) * 512 + c4);
#pragma unroll
  for (int p = 0; p < 2; ++p)
    rb[p] = *(const float4*)(W + (size_t)(brow0 + p * 16 + erow) * 512 + c4);

  for (int kc = 0; kc < 512; kc += 64) {
#pragma unroll
    for (int p = 0; p < 4; ++p) {
      int row = p * 16 + erow;
      int col = c4 ^ ((row & 7) << 3);
      float4 va = ra[p];
      bf16x4 ba = {(__bf16)va.x, (__bf16)va.y, (__bf16)va.z, (__bf16)va.w};
      *(bf16x4*)&As[row][col] = ba;
    }
#pragma unroll
    for (int p = 0; p < 2; ++p) {
      int row = p * 16 + erow;
      int col = c4 ^ ((row & 7) << 3);
      float4 vb = rb[p];
      bf16x4 bb = {(__bf16)vb.x, (__bf16)vb.y, (__bf16)vb.z, (__bf16)vb.w};
      *(bf16x4*)&Bs[row][col] = bb;
    }
    __syncthreads();
    // issue next-tile global loads AFTER the barrier: they fly under the MFMAs
    if (kc < 448) {
#pragma unroll
      for (int p = 0; p < 4; ++p)
        ra[p] = *(const float4*)(x + (size_t)(arow0 + p * 16 + erow) * 512 + kc + 64 + c4);
#pragma unroll
      for (int p = 0; p < 2; ++p)
        rb[p] = *(const float4*)(W + (size_t)(brow0 + p * 16 + erow) * 512 + kc + 64 + c4);
    }
#pragma unroll
    for (int ks = 0; ks < 2; ++ks) {
      bf16x8 af[2], bfr;
#pragma unroll
      for (int f = 0; f < 2; ++f)
        af[f] = *(const bf16x8*)&As[wr * 32 + f * 16 + n16][(ks * 32 + q * 8) ^ sx];
      bfr = *(const bf16x8*)&Bs[wc * 16 + n16][(ks * 32 + q * 8) ^ sx];
      for (int fr = 0; fr < 2; ++fr)
        acc[fr] = __builtin_amdgcn_mfma_f32_16x16x32_bf16(af[fr], bfr, acc[fr], 0, 0, 0);
    }
    __syncthreads();
  }

  {
    int n_g = bj * 32 + wc * 16 + n16;   // 0..511
    float bv = bias[n_g];
    int l = n_g >> 8, o = n_g & 255;
    for (int fr = 0; fr < 2; ++fr) {
      for (int r = 0; r < 4; ++r) {
        int m_g = bi * 64 + wr * 32 + fr * 16 + q * 4 + r;
        float v = acc[fr][r] + bv;
        totalbf[tbidx(l * 4096 + m_g, o)] = (__bf16)v;
      }
    }
  }
}

// ------- fused: gates + sq + colsum + combine + bandwidth finalize ------------
// R11-EXACT structure (~6 us by fill-accounting): 128 blocks, wave owns 8
// rows (deep unrolled ILP — 8 independent load chains), atomic colsum (32K
// total RMWs, fine at this count; R12's 131K and R13's serial-partial-sum
// finalizer were both worse). Single change vs R11: SIGMOID gates —
// softmax over 2 logits = sigmoid(x.(w0-w1)+(b0-b1)): half dot FLOPs,
// 6-shuffle reduce instead of 12.
__global__ __launch_bounds__(256) void k_sqc(const __bf16* __restrict__ tot,
                                             const float* __restrict__ x,
                                             const float* __restrict__ Waux,
                                             const float* __restrict__ baux,
                                             float* __restrict__ sq,
                                             float* __restrict__ colsum,
                                             float* __restrict__ scal,
                                             float* __restrict__ out) {
  __shared__ float lcol[4][256];
  __shared__ float wsq[4];
  __shared__ unsigned int isLast;
  const int t = threadIdx.x;
  const int wave = t >> 6, lane = t & 63;

  // ---- gates: d = x.(w0-w1) + (b0-b1); g0 = sigmoid(d), g1 = 1-g0 ----
  const float4* wa = (const float4*)(Waux);          // row 0: 128 float4
  const float4* wb = (const float4*)(Waux + 512);    // row 1
  float4 wa0 = wa[lane * 2], wa1 = wa[lane * 2 + 1];
  float4 wb0 = wb[lane * 2], wb1 = wb[lane * 2 + 1];
  float4 wd0 = {wa0.x - wb0.x, wa0.y - wb0.y, wa0.z - wb0.z, wa0.w - wb0.w};
  float4 wd1 = {wa1.x - wb1.x, wa1.y - wb1.y, wa1.z - wb1.z, wa1.w - wb1.w};
  const float bd = baux[0] - baux[1];
  float g0[8], g1[8];
#pragma unroll
  for (int it = 0; it < 8; ++it) {
    int m = blockIdx.x * 32 + wave * 8 + it;
    const float4* xr = (const float4*)(x + (size_t)m * 512);
    float4 x0 = xr[lane * 2], x1 = xr[lane * 2 + 1];
    float d = x0.x * wd0.x + x0.y * wd0.y + x0.z * wd0.z + x0.w * wd0.w
            + x1.x * wd1.x + x1.y * wd1.y + x1.z * wd1.z + x1.w * wd1.w;
    for (int off = 32; off; off >>= 1) d += __shfl_xor(d, off, 64);
    d += bd;
    float g = 1.f / (1.f + __expf(-d));
    g0[it] = g;
    g1[it] = 1.f - g;
  }

  // ---- sq + colsum + combine ----
  float c0 = 0.f, c1 = 0.f, c2 = 0.f, c3 = 0.f;
  float bsq = 0.f;
#pragma unroll
  for (int it = 0; it < 8; ++it) {
    int m = blockIdx.x * 32 + wave * 8 + it;      // 0..4095
    bf16x4 v0 = *(const bf16x4*)(tot + tbidx(m, lane * 4));
    bf16x4 v1 = *(const bf16x4*)(tot + tbidx(4096 + m, lane * 4));
    float f00 = v0[0], f01 = v0[1], f02 = v0[2], f03 = v0[3];
    float f10 = v1[0], f11 = v1[1], f12 = v1[2], f13 = v1[3];
    float s0 = f00 * f00 + f01 * f01 + f02 * f02 + f03 * f03;
    float s1 = f10 * f10 + f11 * f11 + f12 * f12 + f13 * f13;
    for (int off = 32; off; off >>= 1) {
      s0 += __shfl_down(s0, off, 64);
      s1 += __shfl_down(s1, off, 64);
    }
    if (lane == 0) { sq[m] = s0; sq[4096 + m] = s1; bsq += s0 + s1; }
    c0 += f00 + f10; c1 += f01 + f11; c2 += f02 + f12; c3 += f03 + f13;
    float4 r;
    r.x = g0[it] * f00 + g1[it] * f10;
    r.y = g0[it] * f01 + g1[it] * f11;
    r.z = g0[it] * f02 + g1[it] * f12;
    r.w = g0[it] * f03 + g1[it] * f13;
    *(float4*)(out + (size_t)m * 256 + lane * 4) = r;
  }
  lcol[wave][lane * 4 + 0] = c0;
  lcol[wave][lane * 4 + 1] = c1;
  lcol[wave][lane * 4 + 2] = c2;
  lcol[wave][lane * 4 + 3] = c3;
  if (lane == 0) wsq[wave] = bsq;
  __syncthreads();
  float s2 = lcol[0][t] + lcol[1][t] + lcol[2][t] + lcol[3][t];
  atomicAdd(&colsum[t], s2);
  if (t == 0) atomicAdd(&scal[4], wsq[0] + wsq[1] + wsq[2] + wsq[3]);
  __threadfence();
  if (t == 0) {
    unsigned int c = atomicAdd((unsigned int*)(scal + 5), 1u);
    isLast = (c == 127u) ? 1u : 0u;
  }
  __syncthreads();
  if (isLast) {
    __threadfence();
    float cv = atomicAdd(&colsum[t], 0.0f);      // coherent read
    lcol[0][t] = cv * cv;
    __syncthreads();
    for (int off = 128; off; off >>= 1) {
      if (t < off) lcol[0][t] += lcol[0][t + off];
      __syncthreads();
    }
    if (t == 0) {
      float sumsq = atomicAdd(&scal[4], 0.0f);
      double sumdist = 2.0 * 8192.0 * (double)sumsq - 2.0 * (double)lcol[0][0];
      double bw = sumdist / (8192.0 * 8192.0 - 8192.0) / 4.0;  // / KERNEL_MUL^(5//2)
      scal[1] = (float)(1.4426950408889634 / (bw * 16.0));     // g4 * log2(e)
      scal[2] = (float)bw;
    }
  }
}

// ---------------- Gram tiles + fused multi-bandwidth kernel sum ---------------
// R11-proven direct-fragment (45.1 us): fragment-major totalbf, each 16x32
// A/B fragment is ONE coalesced 1KB wave-load; no LDS tiles, no barriers.
// Triangular XCD-chunked grid, fire-and-forget atomic with final scale folded
// in. UNCHANGED.
__global__ __launch_bounds__(256) void k_gram(const __bf16* __restrict__ tot,
                                              const float* __restrict__ sq,
                                              const float* __restrict__ scal,
                                              float* __restrict__ out) {
  const int b = blockIdx.x;                    // 0..2079
  const int nid = (b & 7) * 260 + (b >> 3);    // XCD-chunked, bijective (2080=8*260)
  int ti = (int)((129.0 - sqrt(129.0 * 129.0 - 8.0 * (double)nid)) * 0.5);
  while (64 * ti - ti * (ti - 1) / 2 > nid) --ti;
  while (64 * (ti + 1) - (ti + 1) * ti / 2 <= nid) ++ti;
  const int tj = ti + (nid - (64 * ti - ti * (ti - 1) / 2));

  __shared__ float sqi[128], sqj[128];
  __shared__ float wred[4];
  const int t = threadIdx.x;
  const int wid = t >> 6, lane = t & 63;
  const int wr = wid >> 1, wc = wid & 1;
  const int n16 = lane & 15, q = lane >> 4;

  const float g = scal[1];           // log2e / (bw*16)
  if (t < 128) sqi[t] = sq[ti * 128 + t] * g;          // pre-scaled by g
  else         sqj[t - 128] = sq[tj * 128 + (t - 128)] * g;

  f32x4 acc[4][4];
  f32x4 zero = {0.f, 0.f, 0.f, 0.f};
  for (int i = 0; i < 4; ++i)
    for (int j = 0; j < 4; ++j) acc[i][j] = zero;

  // fragment bases: A-frag f covers rows ti*128+wr*64+f*16..+16 — row-block
  // (ti*8+wr*4+f); lane l's 16B slice at +l*8 elems; col-block ks at +ks*512.
  const __bf16* pA = tot + ((size_t)(ti * 8 + wr * 4) << 12) + lane * 8;
  const __bf16* pB = tot + ((size_t)(tj * 8 + wc * 4) << 12) + lane * 8;

#pragma unroll
  for (int ks = 0; ks < 8; ++ks) {
    bf16x8 af[4], bfr[4];
#pragma unroll
    for (int f = 0; f < 4; ++f) {
      af[f]  = *(const bf16x8*)(pA + ((size_t)f << 12) + ((size_t)ks << 9));
      bfr[f] = *(const bf16x8*)(pB + ((size_t)f << 12) + ((size_t)ks << 9));
    }
    for (int fr = 0; fr < 4; ++fr)
      for (int fc = 0; fc < 4; ++fc)
        acc[fr][fc] = __builtin_amdgcn_mfma_f32_16x16x32_bf16(af[fr], bfr[fc], acc[fr][fc], 0, 0, 0);
  }

  __syncthreads();   // publish sqi/sqj (cross-wave)

  // epilogue: arg = 2g*acc - (g*si + g*sj); ksum = u+u2+u4+u8+u16, u=exp2(arg)
  const float twog = 2.f * g;
  float lsum = 0.f;
  for (int fr = 0; fr < 4; ++fr) {
    for (int r = 0; r < 4; ++r) {
      float gsi = sqi[wr * 64 + fr * 16 + q * 4 + r];
      for (int fc = 0; fc < 4; ++fc) {
        float gsj = sqj[wc * 64 + fc * 16 + n16];
        float u = exp2f(fmaf(twog, acc[fr][fc][r], -(gsi + gsj)));
        float u2 = u * u, u4 = u2 * u2, u8 = u4 * u4;
        float s1 = fmaf(u8, u8, u8);           // u16 + u8
        lsum += (u + u2) + (u4 + s1);
      }
    }
  }
  for (int off = 32; off; off >>= 1) lsum += __shfl_down(lsum, off, 64);
  if (lane == 0) wred[wid] = lsum;
  __syncthreads();
  if (t == 0) {
    float blocksum = wred[0] + wred[1] + wred[2] + wred[3];
    float sgn = ((ti < 32) == (tj < 32)) ? 1.f : -1.f;
    float wgt = (ti == tj) ? sgn : 2.f * sgn;
    // final scale folded in: out[1048576] = -S/2^24, accumulated directly
    atomicAdd(out + 1048576, wgt * blocksum * (-1.f / 16777216.f));
  }
}

extern "C" void kernel_launch(void* const* d_in, const int* in_sizes, int n_in,
                              void* d_out, int out_size, void* d_ws, size_t ws_size,
                              hipStream_t stream) {
  const float* x    = (const float*)d_in[0];
  const float* Waux = (const float*)d_in[1];
  const float* baux = (const float*)d_in[2];
  const float* W    = (const float*)d_in[3];
  const float* bias = (const float*)d_in[4];
  float* out = (float*)d_out;

  char* ws = (char*)d_ws;
  __bf16* totalbf = (__bf16*)ws;                    // 8192*256*2 = 4,194,304 B (tiled)
  float* sq      = (float*)(ws + 4194304);          // 8192 f32
  float* colsum  = (float*)(ws + 4227072);          // 256 f32
  float* scal    = (float*)(ws + 4228096);          // [1]=g4l2 [2]=bw [4]=sumsq [5]=cnt

  k_outs<<<dim3(16, 64), 256, 0, stream>>>(x, W, bias, totalbf, colsum, scal, out);
  k_sqc<<<128, 256, 0, stream>>>(totalbf, x, Waux, baux, sq, colsum, scal, out);
  k_gram<<<2080, 256, 0, stream>>>(totalbf, sq, scal, out);
}

// Round 15
// 138.862 us; speedup vs baseline: 1.2861x; 1.0089x over previous
//
#include <hip/hip_runtime.h>
#include <stdint.h>
#include <math.h>

typedef __attribute__((ext_vector_type(8))) __bf16 bf16x8;
typedef __attribute__((ext_vector_type(4))) __bf16 bf16x4;
typedef __attribute__((ext_vector_type(4))) float f32x4;

// -------- fragment-major tiled layout for totalbf --------
// 16-row x 32-col fragment blocks in MFMA order. Element (row, o):
//   row-block = row>>4 (4096 elems), col-block = o>>5 (512 elems),
//   inner = q<<7 | n16<<3 | e  with q=(o>>3)&3, n16=row&15, e=o&7.
// Lane l = q*16+n16 owns the 8 elems at +l*8: one 16x32 fragment = ONE
// coalesced 1KB wave-load (dwordx4/lane). Verified R11.
__device__ __forceinline__ size_t tbidx(int row, int o) {
  return ((size_t)(row >> 4) << 12) + ((o >> 5) << 9) +
         (((o >> 3) & 3) << 7) + ((row & 15) << 3) + (o & 7);
}

// ---------------- outs GEMM: C[m][n] = sum_k x[m][k] * Wflat[n][k] + bias[n] ----
// R14-proven: 64x32 tiles, grid (16,64) = 1024 blocks = 4 blocks/CU.
// Reg-staged bf16, XOR swizzle, prefetch-after-barrier; fragment-major store.
// Block (0,0) zero-inits colsum + scal + final scalar. UNCHANGED.
__global__ __launch_bounds__(256) void k_outs(const float* __restrict__ x,
                                              const float* __restrict__ W,
                                              const float* __restrict__ bias,
                                              __bf16* __restrict__ totalbf,
                                              float* __restrict__ colsum,
                                              float* __restrict__ scal,
                                              float* __restrict__ out) {
  __shared__ __bf16 As[64][64];   // M-rows x K
  __shared__ __bf16 Bs[32][64];   // N-rows x K
  const int bj = blockIdx.x;   // 0..15 (N tiles of 32)
  const int bi = blockIdx.y;   // 0..63 (M tiles of 64)
  const int t = threadIdx.x;
  if (bj == 0 && bi == 0) {
    colsum[t] = 0.f;
    if (t < 8) scal[t] = 0.f;
    if (t == 0) out[1048576] = 0.f;
  }
  const int wid = t >> 6, lane = t & 63;
  const int wr = wid >> 1, wc = wid & 1;
  const int n16 = lane & 15, q = lane >> 4;
  const int sx = (n16 & 7) << 3;        // read-side swizzle (element units)
  const int erow = t >> 4;              // 0..15 (+p*16)
  const int c4 = (t & 15) << 2;         // 0..60

  f32x4 acc[2];
  f32x4 zero = {0.f, 0.f, 0.f, 0.f};
  acc[0] = zero; acc[1] = zero;

  const int arow0 = bi * 64, brow0 = bj * 32;

  float4 ra[4], rb[2];
#pragma unroll
  for (int p = 0; p < 4; ++p)
    ra[p] = *(const float4*)(x + (size_t)(arow0 + p * 16 + erow) * 512 + c4);
#pragma unroll
  for (int p = 0; p < 2; ++p)
    rb[p] = *(const float4*)(W + (size_t)(brow0 + p * 16 + erow) * 512 + c4);

  for (int kc = 0; kc < 512; kc += 64) {
#pragma unroll
    for (int p = 0; p < 4; ++p) {
      int row = p * 16 + erow;
      int col = c4 ^ ((row & 7) << 3);
      float4 va = ra[p];
      bf16x4 ba = {(__bf16)va.x, (__bf16)va.y, (__bf16)va.z, (__bf16)va.w};
      *(bf16x4*)&As[row][col] = ba;
    }
#pragma unroll
    for (int p = 0; p < 2; ++p) {
      int row = p * 16 + erow;
      int col = c4 ^ ((row & 7) << 3);
      float4 vb = rb[p];
      bf16x4 bb = {(__bf16)vb.x, (__bf16)vb.y, (__bf16)vb.z, (__bf16)vb.w};
      *(bf16x4*)&Bs[row][col] = bb;
    }
    __syncthreads();
    // issue next-tile global loads AFTER the barrier: they fly under the MFMAs
    if (kc < 448) {
#pragma unroll
      for (int p = 0; p < 4; ++p)
        ra[p] = *(const float4*)(x + (size_t)(arow0 + p * 16 + erow) * 512 + kc + 64 + c4);
#pragma unroll
      for (int p = 0; p < 2; ++p)
        rb[p] = *(const float4*)(W + (size_t)(brow0 + p * 16 + erow) * 512 + kc + 64 + c4);
    }
#pragma unroll
    for (int ks = 0; ks < 2; ++ks) {
      bf16x8 af[2], bfr;
#pragma unroll
      for (int f = 0; f < 2; ++f)
        af[f] = *(const bf16x8*)&As[wr * 32 + f * 16 + n16][(ks * 32 + q * 8) ^ sx];
      bfr = *(const bf16x8*)&Bs[wc * 16 + n16][(ks * 32 + q * 8) ^ sx];
      for (int fr = 0; fr < 2; ++fr)
        acc[fr] = __builtin_amdgcn_mfma_f32_16x16x32_bf16(af[fr], bfr, acc[fr], 0, 0, 0);
    }
    __syncthreads();
  }

  {
    int n_g = bj * 32 + wc * 16 + n16;   // 0..511
    float bv = bias[n_g];
    int l = n_g >> 8, o = n_g & 255;
    for (int fr = 0; fr < 2; ++fr) {
      for (int r = 0; r < 4; ++r) {
        int m_g = bi * 64 + wr * 32 + fr * 16 + q * 4 + r;
        float v = acc[fr][r] + bv;
        totalbf[tbidx(l * 4096 + m_g, o)] = (__bf16)v;
      }
    }
  }
}

// ------- fused: gates + sq + colsum + combine + bandwidth finalize ------------
// R14-proven: 128 blocks, 8 rows/wave ILP, sigmoid gates, atomic colsum
// (32K RMWs fine), last-block bandwidth finalize. UNCHANGED.
__global__ __launch_bounds__(256) void k_sqc(const __bf16* __restrict__ tot,
                                             const float* __restrict__ x,
                                             const float* __restrict__ Waux,
                                             const float* __restrict__ baux,
                                             float* __restrict__ sq,
                                             float* __restrict__ colsum,
                                             float* __restrict__ scal,
                                             float* __restrict__ out) {
  __shared__ float lcol[4][256];
  __shared__ float wsq[4];
  __shared__ unsigned int isLast;
  const int t = threadIdx.x;
  const int wave = t >> 6, lane = t & 63;

  // ---- gates: d = x.(w0-w1) + (b0-b1); g0 = sigmoid(d), g1 = 1-g0 ----
  const float4* wa = (const float4*)(Waux);          // row 0: 128 float4
  const float4* wb = (const float4*)(Waux + 512);    // row 1
  float4 wa0 = wa[lane * 2], wa1 = wa[lane * 2 + 1];
  float4 wb0 = wb[lane * 2], wb1 = wb[lane * 2 + 1];
  float4 wd0 = {wa0.x - wb0.x, wa0.y - wb0.y, wa0.z - wb0.z, wa0.w - wb0.w};
  float4 wd1 = {wa1.x - wb1.x, wa1.y - wb1.y, wa1.z - wb1.z, wa1.w - wb1.w};
  const float bd = baux[0] - baux[1];
  float g0[8], g1[8];
#pragma unroll
  for (int it = 0; it < 8; ++it) {
    int m = blockIdx.x * 32 + wave * 8 + it;
    const float4* xr = (const float4*)(x + (size_t)m * 512);
    float4 x0 = xr[lane * 2], x1 = xr[lane * 2 + 1];
    float d = x0.x * wd0.x + x0.y * wd0.y + x0.z * wd0.z + x0.w * wd0.w
            + x1.x * wd1.x + x1.y * wd1.y + x1.z * wd1.z + x1.w * wd1.w;
    for (int off = 32; off; off >>= 1) d += __shfl_xor(d, off, 64);
    d += bd;
    float g = 1.f / (1.f + __expf(-d));
    g0[it] = g;
    g1[it] = 1.f - g;
  }

  // ---- sq + colsum + combine ----
  float c0 = 0.f, c1 = 0.f, c2 = 0.f, c3 = 0.f;
  float bsq = 0.f;
#pragma unroll
  for (int it = 0; it < 8; ++it) {
    int m = blockIdx.x * 32 + wave * 8 + it;      // 0..4095
    bf16x4 v0 = *(const bf16x4*)(tot + tbidx(m, lane * 4));
    bf16x4 v1 = *(const bf16x4*)(tot + tbidx(4096 + m, lane * 4));
    float f00 = v0[0], f01 = v0[1], f02 = v0[2], f03 = v0[3];
    float f10 = v1[0], f11 = v1[1], f12 = v1[2], f13 = v1[3];
    float s0 = f00 * f00 + f01 * f01 + f02 * f02 + f03 * f03;
    float s1 = f10 * f10 + f11 * f11 + f12 * f12 + f13 * f13;
    for (int off = 32; off; off >>= 1) {
      s0 += __shfl_down(s0, off, 64);
      s1 += __shfl_down(s1, off, 64);
    }
    if (lane == 0) { sq[m] = s0; sq[4096 + m] = s1; bsq += s0 + s1; }
    c0 += f00 + f10; c1 += f01 + f11; c2 += f02 + f12; c3 += f03 + f13;
    float4 r;
    r.x = g0[it] * f00 + g1[it] * f10;
    r.y = g0[it] * f01 + g1[it] * f11;
    r.z = g0[it] * f02 + g1[it] * f12;
    r.w = g0[it] * f03 + g1[it] * f13;
    *(float4*)(out + (size_t)m * 256 + lane * 4) = r;
  }
  lcol[wave][lane * 4 + 0] = c0;
  lcol[wave][lane * 4 + 1] = c1;
  lcol[wave][lane * 4 + 2] = c2;
  lcol[wave][lane * 4 + 3] = c3;
  if (lane == 0) wsq[wave] = bsq;
  __syncthreads();
  float s2 = lcol[0][t] + lcol[1][t] + lcol[2][t] + lcol[3][t];
  atomicAdd(&colsum[t], s2);
  if (t == 0) atomicAdd(&scal[4], wsq[0] + wsq[1] + wsq[2] + wsq[3]);
  __threadfence();
  if (t == 0) {
    unsigned int c = atomicAdd((unsigned int*)(scal + 5), 1u);
    isLast = (c == 127u) ? 1u : 0u;
  }
  __syncthreads();
  if (isLast) {
    __threadfence();
    float cv = atomicAdd(&colsum[t], 0.0f);      // coherent read
    lcol[0][t] = cv * cv;
    __syncthreads();
    for (int off = 128; off; off >>= 1) {
      if (t < off) lcol[0][t] += lcol[0][t + off];
      __syncthreads();
    }
    if (t == 0) {
      float sumsq = atomicAdd(&scal[4], 0.0f);
      double sumdist = 2.0 * 8192.0 * (double)sumsq - 2.0 * (double)lcol[0][0];
      double bw = sumdist / (8192.0 * 8192.0 - 8192.0) / 4.0;  // / KERNEL_MUL^(5//2)
      scal[1] = (float)(1.4426950408889634 / (bw * 16.0));     // g4 * log2(e)
      scal[2] = (float)bw;
    }
  }
}

// ---------------- Gram tiles + fused multi-bandwidth kernel sum ---------------
// R15: direct-fragment + EXPLICIT 2-deep register pipeline. R14 counters
// (VGPR=84 < 64 acc + 32 frags, MfmaUtil 14%, mem-wait ~47%) show the
// compiler allocated NO prefetch registers — each ks's 8 loads were waited on
// before its 16 MFMAs (8 exposed L2 latencies/wave). Prefetch ks+1 into a
// second named fragment set while MFMAs consume ks; all indexing is
// compile-time (full unroll) so regs stay allocated (rule #20 safe).
__global__ __launch_bounds__(256) void k_gram(const __bf16* __restrict__ tot,
                                              const float* __restrict__ sq,
                                              const float* __restrict__ scal,
                                              float* __restrict__ out) {
  const int b = blockIdx.x;                    // 0..2079
  const int nid = (b & 7) * 260 + (b >> 3);    // XCD-chunked, bijective (2080=8*260)
  int ti = (int)((129.0 - sqrt(129.0 * 129.0 - 8.0 * (double)nid)) * 0.5);
  while (64 * ti - ti * (ti - 1) / 2 > nid) --ti;
  while (64 * (ti + 1) - (ti + 1) * ti / 2 <= nid) ++ti;
  const int tj = ti + (nid - (64 * ti - ti * (ti - 1) / 2));

  __shared__ float sqi[128], sqj[128];
  __shared__ float wred[4];
  const int t = threadIdx.x;
  const int wid = t >> 6, lane = t & 63;
  const int wr = wid >> 1, wc = wid & 1;
  const int n16 = lane & 15, q = lane >> 4;

  const float g = scal[1];           // log2e / (bw*16)
  if (t < 128) sqi[t] = sq[ti * 128 + t] * g;          // pre-scaled by g
  else         sqj[t - 128] = sq[tj * 128 + (t - 128)] * g;

  f32x4 acc[4][4];
  f32x4 zero = {0.f, 0.f, 0.f, 0.f};
  for (int i = 0; i < 4; ++i)
    for (int j = 0; j < 4; ++j) acc[i][j] = zero;

  // fragment bases: A-frag f covers rows ti*128+wr*64+f*16..+16 — row-block
  // (ti*8+wr*4+f); lane l's 16B slice at +l*8 elems; col-block ks at +ks*512.
  const __bf16* pA = tot + ((size_t)(ti * 8 + wr * 4) << 12) + lane * 8;
  const __bf16* pB = tot + ((size_t)(tj * 8 + wc * 4) << 12) + lane * 8;

  bf16x8 aE[4], bE[4], aO[4], bO[4];   // even/odd ks fragment sets
#pragma unroll
  for (int f = 0; f < 4; ++f) {
    aE[f] = *(const bf16x8*)(pA + ((size_t)f << 12));
    bE[f] = *(const bf16x8*)(pB + ((size_t)f << 12));
  }
#pragma unroll
  for (int ks = 0; ks < 8; ++ks) {
    // prefetch ks+1 into the other set (in flight during this ks's MFMAs)
    if (ks < 7) {
      if ((ks & 1) == 0) {
#pragma unroll
        for (int f = 0; f < 4; ++f) {
          aO[f] = *(const bf16x8*)(pA + ((size_t)f << 12) + ((size_t)(ks + 1) << 9));
          bO[f] = *(const bf16x8*)(pB + ((size_t)f << 12) + ((size_t)(ks + 1) << 9));
        }
      } else {
#pragma unroll
        for (int f = 0; f < 4; ++f) {
          aE[f] = *(const bf16x8*)(pA + ((size_t)f << 12) + ((size_t)(ks + 1) << 9));
          bE[f] = *(const bf16x8*)(pB + ((size_t)f << 12) + ((size_t)(ks + 1) << 9));
        }
      }
    }
    if ((ks & 1) == 0) {
      for (int fr = 0; fr < 4; ++fr)
        for (int fc = 0; fc < 4; ++fc)
          acc[fr][fc] = __builtin_amdgcn_mfma_f32_16x16x32_bf16(aE[fr], bE[fc], acc[fr][fc], 0, 0, 0);
    } else {
      for (int fr = 0; fr < 4; ++fr)
        for (int fc = 0; fc < 4; ++fc)
          acc[fr][fc] = __builtin_amdgcn_mfma_f32_16x16x32_bf16(aO[fr], bO[fc], acc[fr][fc], 0, 0, 0);
    }
  }

  __syncthreads();   // publish sqi/sqj (cross-wave)

  // epilogue: arg = 2g*acc - (g*si + g*sj); ksum = u+u2+u4+u8+u16, u=exp2(arg)
  const float twog = 2.f * g;
  float lsum = 0.f;
  for (int fr = 0; fr < 4; ++fr) {
    for (int r = 0; r < 4; ++r) {
      float gsi = sqi[wr * 64 + fr * 16 + q * 4 + r];
      for (int fc = 0; fc < 4; ++fc) {
        float gsj = sqj[wc * 64 + fc * 16 + n16];
        float u = exp2f(fmaf(twog, acc[fr][fc][r], -(gsi + gsj)));
        float u2 = u * u, u4 = u2 * u2, u8 = u4 * u4;
        float s1 = fmaf(u8, u8, u8);           // u16 + u8
        lsum += (u + u2) + (u4 + s1);
      }
    }
  }
  for (int off = 32; off; off >>= 1) lsum += __shfl_down(lsum, off, 64);
  if (lane == 0) wred[wid] = lsum;
  __syncthreads();
  if (t == 0) {
    float blocksum = wred[0] + wred[1] + wred[2] + wred[3];
    float sgn = ((ti < 32) == (tj < 32)) ? 1.f : -1.f;
    float wgt = (ti == tj) ? sgn : 2.f * sgn;
    // final scale folded in: out[1048576] = -S/2^24, accumulated directly
    atomicAdd(out + 1048576, wgt * blocksum * (-1.f / 16777216.f));
  }
}

extern "C" void kernel_launch(void* const* d_in, const int* in_sizes, int n_in,
                              void* d_out, int out_size, void* d_ws, size_t ws_size,
                              hipStream_t stream) {
  const float* x    = (const float*)d_in[0];
  const float* Waux = (const float*)d_in[1];
  const float* baux = (const float*)d_in[2];
  const float* W    = (const float*)d_in[3];
  const float* bias = (const float*)d_in[4];
  float* out = (float*)d_out;

  char* ws = (char*)d_ws;
  __bf16* totalbf = (__bf16*)ws;                    // 8192*256*2 = 4,194,304 B (tiled)
  float* sq      = (float*)(ws + 4194304);          // 8192 f32
  float* colsum  = (float*)(ws + 4227072);          // 256 f32
  float* scal    = (float*)(ws + 4228096);          // [1]=g4l2 [2]=bw [4]=sumsq [5]=cnt

  k_outs<<<dim3(16, 64), 256, 0, stream>>>(x, W, bias, totalbf, colsum, scal, out);
  k_sqc<<<128, 256, 0, stream>>>(totalbf, x, Waux, baux, sq, colsum, scal, out);
  k_gram<<<2080, 256, 0, stream>>>(totalbf, sq, scal, out);
}